// Round 6
// baseline (887.913 us; speedup 1.0000x reference)
//
#include <hip/hip_runtime.h>

#define D     12
#define ASTR  13     // LDS acc stride (coprime with 32 banks)
#define EPB   2048   // edges per block for passes A/B
#define ABLK  256
#define SBLK  256
#define CBLK  256
#define SPLIT 4      // blocks per bucket in fallback pass C

// ---------------- pass A: per-block bucket histogram ----------------
__global__ __launch_bounds__(ABLK) void passA_hist(
    const int* __restrict__ receivers, long E, int nbuck,
    int* __restrict__ cnt /* [nblk][nbuck], row-major */)
{
    extern __shared__ int hist[]; // nbuck ints
    for (int i = threadIdx.x; i < nbuck; i += ABLK) hist[i] = 0;
    __syncthreads();
    long e0 = (long)blockIdx.x * EPB;
    long e1 = e0 + EPB; if (e1 > E) e1 = E;
    for (long e = e0 + threadIdx.x; e < e1; e += ABLK) {
        int r = receivers[e];
        atomicAdd(&hist[r >> 7], 1);
    }
    __syncthreads();
    int* row = cnt + (long)blockIdx.x * nbuck;
    for (int i = threadIdx.x; i < nbuck; i += ABLK) row[i] = hist[i];
}

// ---------------- pass S1: exclusive scan down each bucket column ----------------
__global__ __launch_bounds__(SBLK) void passS1_colscan(
    int* __restrict__ cnt, int nblk, int nbuck, int* __restrict__ totals)
{
    int b = blockIdx.x;
    int t = threadIdx.x;
    __shared__ int csum[SBLK];
    int per = (nblk + SBLK - 1) / SBLK;
    int i0 = t * per;
    int i1 = i0 + per; if (i1 > nblk) i1 = nblk;
    int s = 0;
    for (int i = i0; i < i1; ++i) s += cnt[(long)i * nbuck + b];
    csum[t] = s;
    __syncthreads();
    for (int off = 1; off < SBLK; off <<= 1) {
        int add = (t >= off) ? csum[t - off] : 0;
        __syncthreads();
        csum[t] += add;
        __syncthreads();
    }
    int run = csum[t] - s;
    for (int i = i0; i < i1; ++i) {
        long a = (long)i * nbuck + b;
        int tmp = cnt[a];
        cnt[a] = run;
        run += tmp;
    }
    if (t == SBLK - 1) totals[b] = csum[SBLK - 1];
}

// ---------------- pass S2: exclusive scan over bucket totals ----------------
__global__ __launch_bounds__(1024) void passS2_basescan(
    const int* __restrict__ totals, int* __restrict__ base, int nbuck)
{
    __shared__ int sh[1024];
    int t = threadIdx.x;
    int v = (t < nbuck) ? totals[t] : 0;
    sh[t] = v;
    __syncthreads();
    for (int off = 1; off < 1024; off <<= 1) {
        int add = (t >= off) ? sh[t - off] : 0;
        __syncthreads();
        sh[t] += add;
        __syncthreads();
    }
    if (t < nbuck) base[t] = sh[t] - v;
}

// -------- helpers --------
__device__ __forceinline__ void build_weights(
    int t,
    const float* __restrict__ bn_scale, const float* __restrict__ bn_bias,
    const float* __restrict__ bn_mean,  const float* __restrict__ bn_var,
    const float* __restrict__ W1, const float* __restrict__ b1,
    const float* __restrict__ W2, const float* __restrict__ b2,
    float* sW1, float* sW2, float* sB1, float* sB2)
{
    if (t < D * D) {
        int d = t / D;
        float a = bn_scale[d] * rsqrtf(bn_var[d] + 1e-5f);
        sW1[t] = a * W1[t];
        sW2[t] = W2[t];
    }
    if (t < D) {
        float acc = b1[t];
        #pragma unroll
        for (int d = 0; d < D; ++d) {
            float a = bn_scale[d] * rsqrtf(bn_var[d] + 1e-5f);
            float c = bn_bias[d] - bn_mean[d] * a;
            acc += c * W1[d * D + t];
        }
        sB1[t] = acc;
        sB2[t] = b2[t];
    }
}

__device__ __forceinline__ void mlp12(
    const float x[D],
    const float* sW1, const float* sW2, const float* sB1, const float* sB2,
    float y[D])
{
    float h[D];
    #pragma unroll
    for (int j = 0; j < D; ++j) h[j] = sB1[j];
    #pragma unroll
    for (int d = 0; d < D; ++d) {
        float xd = x[d];
        #pragma unroll
        for (int j = 0; j < D; ++j) h[j] = fmaf(xd, sW1[d * D + j], h[j]);
    }
    #pragma unroll
    for (int j = 0; j < D; ++j) h[j] = fmaxf(h[j], 0.f);
    #pragma unroll
    for (int j = 0; j < D; ++j) y[j] = sB2[j];
    #pragma unroll
    for (int d = 0; d < D; ++d) {
        float hd = h[d];
        #pragma unroll
        for (int j = 0; j < D; ++j) y[j] = fmaf(hd, sW2[d * D + j], y[j]);
    }
}

static __device__ __forceinline__ unsigned f2bf(float f) {
    union { float f; unsigned u; } v; v.f = f;
    unsigned r = v.u + 0x7FFFu + ((v.u >> 16) & 1u);   // RNE
    return r >> 16;
}
static __device__ __forceinline__ float bf_lo(unsigned u) {
    union { unsigned u; float f; } v; v.u = u << 16; return v.f;
}
static __device__ __forceinline__ float bf_hi(unsigned u) {
    union { unsigned u; float f; } v; v.u = u & 0xFFFF0000u; return v.f;
}

// ---------------- pass B (fused): stream edges, MLP, scatter bf16 message ----------------
// Random access is a fire-and-forget 32B STORE (latency-insensitive), not a gather.
// Row layout (32B): [12 bf16 y | u32 rloc | u32 pad]
__global__ __launch_bounds__(ABLK) void passB_mlp(
    const float* __restrict__ edges, const int* __restrict__ receivers,
    long E, int nbuck,
    const int* __restrict__ cnt, const int* __restrict__ base,
    const float* __restrict__ bn_scale, const float* __restrict__ bn_bias,
    const float* __restrict__ bn_mean,  const float* __restrict__ bn_var,
    const float* __restrict__ W1, const float* __restrict__ b1,
    const float* __restrict__ W2, const float* __restrict__ b2,
    uint4* __restrict__ msg)
{
    __shared__ float sW1[D * D], sW2[D * D], sB1[D], sB2[D];
    extern __shared__ int cur[]; // nbuck cursors
    const int t = threadIdx.x;
    const int* row = cnt + (long)blockIdx.x * nbuck;
    for (int i = t; i < nbuck; i += ABLK) cur[i] = row[i] + base[i];
    build_weights(t, bn_scale, bn_bias, bn_mean, bn_var, W1, b1, W2, b2,
                  sW1, sW2, sB1, sB2);
    __syncthreads();

    long e0 = (long)blockIdx.x * EPB;
    long e1 = e0 + EPB; if (e1 > E) e1 = E;
    for (long e = e0 + t; e < e1; e += ABLK) {
        int r = receivers[e];
        int b = r >> 7;
        const float4* p = reinterpret_cast<const float4*>(edges + e * D);
        float4 a0 = p[0], a1 = p[1], a2 = p[2];
        int pos = atomicAdd(&cur[b], 1);

        float x[D] = {a0.x, a0.y, a0.z, a0.w, a1.x, a1.y, a1.z, a1.w,
                      a2.x, a2.y, a2.z, a2.w};
        float y[D];
        mlp12(x, sW1, sW2, sB1, sB2, y);

        uint4 w0, w1;
        w0.x = f2bf(y[0])  | (f2bf(y[1])  << 16);
        w0.y = f2bf(y[2])  | (f2bf(y[3])  << 16);
        w0.z = f2bf(y[4])  | (f2bf(y[5])  << 16);
        w0.w = f2bf(y[6])  | (f2bf(y[7])  << 16);
        w1.x = f2bf(y[8])  | (f2bf(y[9])  << 16);
        w1.y = f2bf(y[10]) | (f2bf(y[11]) << 16);
        w1.z = (unsigned)(r & 127);
        w1.w = 0u;
        uint4* dst = msg + (long)pos * 2;
        dst[0] = w0;
        dst[1] = w1;
    }
}

// ---------------- pass C (new): coalesced stream of sorted messages + LDS reduce ----------------
__global__ __launch_bounds__(CBLK) void passC_accum(
    const uint4* __restrict__ msg,
    const int* __restrict__ base, const int* __restrict__ totals,
    float* __restrict__ out, long total /* N*D */)
{
    __shared__ float acc[128 * ASTR];
    const int t = threadIdx.x;
    for (int i = t; i < 128 * ASTR; i += CBLK) acc[i] = 0.f;
    __syncthreads();

    const int b = blockIdx.x;
    const long s0 = base[b];
    const int n = totals[b];

    for (int k = t; k < n; k += CBLK) {
        const uint4* src = msg + (s0 + k) * 2;
        uint4 w0 = src[0];
        uint4 w1 = src[1];
        float* a = &acc[(int)w1.z * ASTR];
        atomicAdd(&a[0],  bf_lo(w0.x)); atomicAdd(&a[1],  bf_hi(w0.x));
        atomicAdd(&a[2],  bf_lo(w0.y)); atomicAdd(&a[3],  bf_hi(w0.y));
        atomicAdd(&a[4],  bf_lo(w0.z)); atomicAdd(&a[5],  bf_hi(w0.z));
        atomicAdd(&a[6],  bf_lo(w0.w)); atomicAdd(&a[7],  bf_hi(w0.w));
        atomicAdd(&a[8],  bf_lo(w1.x)); atomicAdd(&a[9],  bf_hi(w1.x));
        atomicAdd(&a[10], bf_lo(w1.y)); atomicAdd(&a[11], bf_hi(w1.y));
    }
    __syncthreads();

    long obase = (long)b * (128 * D);
    long cnt_w = total - obase; if (cnt_w > 128 * D) cnt_w = 128 * D;
    for (long i = t; i < cnt_w; i += CBLK)
        out[obase + i] = acc[((int)i / D) * ASTR + ((int)i % D)];
}

// ================= fallback tier 2: round-5 sort + pipelined gather =================
__global__ __launch_bounds__(ABLK) void passB_scatter(
    const int* __restrict__ receivers, long E, int nbuck,
    const int* __restrict__ cnt, const int* __restrict__ base,
    unsigned int* __restrict__ sorted)
{
    extern __shared__ int cur[];
    const int* row = cnt + (long)blockIdx.x * nbuck;
    for (int i = threadIdx.x; i < nbuck; i += ABLK) cur[i] = row[i] + base[i];
    __syncthreads();
    long e0 = (long)blockIdx.x * EPB;
    long e1 = e0 + EPB; if (e1 > E) e1 = E;
    for (long e = e0 + threadIdx.x; e < e1; e += ABLK) {
        int r = receivers[e];
        int b = r >> 7;
        int pos = atomicAdd(&cur[b], 1);
        sorted[pos] = ((unsigned)e << 7) | (unsigned)(r & 127);
    }
}

__device__ __forceinline__ void mlp_accum(
    float4 ra, float4 rb, float4 rc, int rloc,
    const float* sW1, const float* sW2, const float* sB1, const float* sB2,
    float* acc)
{
    float x[D] = {ra.x, ra.y, ra.z, ra.w, rb.x, rb.y, rb.z, rb.w,
                  rc.x, rc.y, rc.z, rc.w};
    float y[D];
    mlp12(x, sW1, sW2, sB1, sB2, y);
    #pragma unroll
    for (int j = 0; j < D; ++j) atomicAdd(&acc[rloc * ASTR + j], y[j]);
}

__global__ __launch_bounds__(CBLK) void passC_gather(
    const float* __restrict__ edges,
    const unsigned int* __restrict__ sorted,
    const int* __restrict__ base, const int* __restrict__ totals,
    const float* __restrict__ bn_scale, const float* __restrict__ bn_bias,
    const float* __restrict__ bn_mean,  const float* __restrict__ bn_var,
    const float* __restrict__ W1, const float* __restrict__ b1,
    const float* __restrict__ W2, const float* __restrict__ b2,
    float* __restrict__ part, float* __restrict__ out,
    long total, long slab)
{
    __shared__ float sW1[D * D], sW2[D * D], sB1[D], sB2[D];
    __shared__ float acc[128 * ASTR];
    const int t = threadIdx.x;
    build_weights(t, bn_scale, bn_bias, bn_mean, bn_var, W1, b1, W2, b2,
                  sW1, sW2, sB1, sB2);
    for (int i = t; i < 128 * ASTR; i += CBLK) acc[i] = 0.f;
    __syncthreads();

    const int b = blockIdx.x;
    const int s = blockIdx.y;
    const int S = gridDim.y;
    const int s0 = base[b];
    const int n  = totals[b];
    const int chunk = (n + S - 1) / S;
    const int k0 = s * chunk;
    int k1 = k0 + chunk; if (k1 > n) k1 = n;

    int k = k0 + t;
    if (k < k1) {
        const int kmax = k1 - 1;
        unsigned sv0 = sorted[s0 + k];
        int kn = k + CBLK; if (kn > kmax) kn = kmax;
        unsigned sv1 = sorted[s0 + kn];
        const float4* p0 = reinterpret_cast<const float4*>(edges + (long)(sv0 >> 7) * D);
        float4 r0a = p0[0], r0b = p0[1], r0c = p0[2];
        for (; k < k1; k += CBLK) {
            int k2 = k + 2 * CBLK; if (k2 > kmax) k2 = kmax;
            unsigned sv2 = sorted[s0 + k2];
            const float4* p1 = reinterpret_cast<const float4*>(edges + (long)(sv1 >> 7) * D);
            float4 r1a = p1[0], r1b = p1[1], r1c = p1[2];
            mlp_accum(r0a, r0b, r0c, (int)(sv0 & 127u), sW1, sW2, sB1, sB2, acc);
            sv0 = sv1; sv1 = sv2;
            r0a = r1a; r0b = r1b; r0c = r1c;
        }
    }
    __syncthreads();

    if (part != nullptr) {
        float* dst = part + (long)s * slab + (long)b * (128 * D);
        for (int i = t; i < 128 * D; i += CBLK) dst[i] = acc[(i / D) * ASTR + (i % D)];
    } else {
        long obase = (long)b * (128 * D);
        long cnt_w = total - obase; if (cnt_w > 128 * D) cnt_w = 128 * D;
        for (long i = t; i < cnt_w; i += CBLK) out[obase + i] = acc[(i / D) * ASTR + (i % D)];
    }
}

__global__ __launch_bounds__(CBLK) void reduce_partials(
    const float* __restrict__ part, float* __restrict__ out,
    long total4, long slab4, int S)
{
    long i = (long)blockIdx.x * CBLK + threadIdx.x;
    if (i >= total4) return;
    const float4* p = reinterpret_cast<const float4*>(part);
    float4 v = p[i];
    for (int s = 1; s < S; ++s) {
        float4 w = p[(long)s * slab4 + i];
        v.x += w.x; v.y += w.y; v.z += w.z; v.w += w.w;
    }
    reinterpret_cast<float4*>(out)[i] = v;
}

// ---------------- fallback tier 3: direct atomic scatter ----------------
#define EPT 4
__global__ __launch_bounds__(ABLK) void edge_mlp_scatter(
    const float* __restrict__ edges,
    const float* __restrict__ bn_scale, const float* __restrict__ bn_bias,
    const float* __restrict__ bn_mean,  const float* __restrict__ bn_var,
    const float* __restrict__ W1, const float* __restrict__ b1,
    const float* __restrict__ W2, const float* __restrict__ b2,
    const int* __restrict__ receivers, float* __restrict__ out, long E)
{
    __shared__ float sW1[D * D], sW2[D * D], sB1[D], sB2[D];
    const int t = threadIdx.x;
    build_weights(t, bn_scale, bn_bias, bn_mean, bn_var, W1, b1, W2, b2,
                  sW1, sW2, sB1, sB2);
    __syncthreads();
    const long basee = (long)blockIdx.x * (ABLK * EPT) + t;
    #pragma unroll
    for (int kk = 0; kk < EPT; ++kk) {
        long e = basee + (long)kk * ABLK;
        if (e >= E) continue;
        int r = receivers[e];
        const float4* p = reinterpret_cast<const float4*>(edges + e * D);
        float4 v0 = p[0], v1 = p[1], v2 = p[2];
        float x[D] = {v0.x, v0.y, v0.z, v0.w, v1.x, v1.y, v1.z, v1.w,
                      v2.x, v2.y, v2.z, v2.w};
        float y[D];
        mlp12(x, sW1, sW2, sB1, sB2, y);
        #pragma unroll
        for (int j = 0; j < D; ++j) atomicAdd(&out[(long)r * D + j], y[j]);
    }
}

extern "C" void kernel_launch(void* const* d_in, const int* in_sizes, int n_in,
                              void* d_out, int out_size, void* d_ws, size_t ws_size,
                              hipStream_t stream) {
    const float* edges     = (const float*)d_in[0];
    const float* bn_scale  = (const float*)d_in[1];
    const float* bn_bias   = (const float*)d_in[2];
    const float* bn_mean   = (const float*)d_in[3];
    const float* bn_var    = (const float*)d_in[4];
    const float* W1        = (const float*)d_in[5];
    const float* b1        = (const float*)d_in[6];
    const float* W2        = (const float*)d_in[7];
    const float* b2        = (const float*)d_in[8];
    const int*   receivers = (const int*)d_in[9];
    float*       out       = (float*)d_out;

    const long E = (long)in_sizes[0] / D;
    const int  N = out_size / D;

    const int  nbuck = (N + 127) >> 7;
    const long nblk  = (E + EPB - 1) / EPB;
    const size_t cntBytes = (size_t)nblk * (size_t)nbuck * 4u;
    const size_t headBytes = cntBytes + 2u * (size_t)nbuck * 4u + 256u;
    const size_t needNew = headBytes + (size_t)E * 32u + 256u;
    const size_t needOld = headBytes + (size_t)E * 4u;
    const size_t slabBytes = (size_t)nbuck * 128u * D * 4u;
    const long total = (long)N * D;

    const bool shapeOK = (nbuck <= 1024) && (E < (1L << 23));

    if (shapeOK && ws_size >= needNew) {
        // ---- new path: fused MLP + scattered bf16 message write, coalesced reduce ----
        char* w = (char*)d_ws;
        int* cnt    = (int*)w;  w += cntBytes;
        int* totals = (int*)w;  w += (size_t)nbuck * 4u;
        int* basep  = (int*)w;  w += (size_t)nbuck * 4u;
        uint4* msg  = (uint4*)(((uintptr_t)w + 255u) & ~(uintptr_t)255u);

        const size_t lds = (size_t)nbuck * 4u;
        passA_hist    <<<dim3((unsigned)nblk), dim3(ABLK), lds, stream>>>(receivers, E, nbuck, cnt);
        passS1_colscan<<<dim3((unsigned)nbuck), dim3(SBLK), 0, stream>>>(cnt, (int)nblk, nbuck, totals);
        passS2_basescan<<<dim3(1), dim3(1024), 0, stream>>>(totals, basep, nbuck);
        passB_mlp     <<<dim3((unsigned)nblk), dim3(ABLK), lds, stream>>>(
            edges, receivers, E, nbuck, cnt, basep,
            bn_scale, bn_bias, bn_mean, bn_var, W1, b1, W2, b2, msg);
        passC_accum   <<<dim3((unsigned)nbuck), dim3(CBLK), 0, stream>>>(
            msg, basep, totals, out, total);
        return;
    }

    if (shapeOK && ws_size >= needOld) {
        // ---- tier 2: round-5 sort + pipelined gather ----
        const size_t fullNeed = needOld + (size_t)SPLIT * slabBytes + 256u;
        const int S = (ws_size >= fullNeed) ? SPLIT : 1;
        char* w = (char*)d_ws;
        int* cnt    = (int*)w;  w += cntBytes;
        int* totals = (int*)w;  w += (size_t)nbuck * 4u;
        int* basep  = (int*)w;  w += (size_t)nbuck * 4u;
        unsigned int* sorted = (unsigned int*)w;  w += (size_t)E * 4u;
        float* part = (S > 1) ? (float*)(((uintptr_t)w + 255u) & ~(uintptr_t)255u) : nullptr;

        const size_t lds = (size_t)nbuck * 4u;
        const long slab = (long)nbuck * 128 * D;
        passA_hist    <<<dim3((unsigned)nblk), dim3(ABLK), lds, stream>>>(receivers, E, nbuck, cnt);
        passS1_colscan<<<dim3((unsigned)nbuck), dim3(SBLK), 0, stream>>>(cnt, (int)nblk, nbuck, totals);
        passS2_basescan<<<dim3(1), dim3(1024), 0, stream>>>(totals, basep, nbuck);
        passB_scatter <<<dim3((unsigned)nblk), dim3(ABLK), lds, stream>>>(receivers, E, nbuck, cnt, basep, sorted);
        passC_gather  <<<dim3((unsigned)nbuck, (unsigned)S), dim3(CBLK), 0, stream>>>(
            edges, sorted, basep, totals,
            bn_scale, bn_bias, bn_mean, bn_var, W1, b1, W2, b2,
            part, out, total, slab);
        if (S > 1) {
            const long total4 = total / 4;
            const long rblocks = (total4 + CBLK - 1) / CBLK;
            reduce_partials<<<dim3((unsigned)rblocks), dim3(CBLK), 0, stream>>>(
                part, out, total4, slab / 4, S);
        }
        return;
    }

    // ---- tier 3: direct atomic scatter ----
    (void)hipMemsetAsync(d_out, 0, (size_t)out_size * sizeof(float), stream);
    const long blocks = (E + (long)(ABLK * EPT) - 1) / (long)(ABLK * EPT);
    edge_mlp_scatter<<<dim3((unsigned)blocks), dim3(ABLK), 0, stream>>>(
        edges, bn_scale, bn_bias, bn_mean, bn_var, W1, b1, W2, b2,
        receivers, out, E);
}

// Round 7
// 372.593 us; speedup vs baseline: 2.3831x; 2.3831x over previous
//
#include <hip/hip_runtime.h>

#define D     12
#define ASTR  13     // LDS acc stride (coprime with 32 banks)
#define NPB   128    // nodes per bucket (rloc = 7 bits)
#define CAP   9216   // max bucket size held in LDS (mean E/nbuck=8184, +11 sigma)
#define EPB   16384  // edges per block for passes A/B
#define ABLK  256
#define SBLK  256
#define CBLK  256

// ---------------- pass A: per-block bucket histogram ----------------
__global__ __launch_bounds__(ABLK) void passA_hist(
    const int* __restrict__ receivers, long E, int nbuck,
    int* __restrict__ cnt /* [nblk][nbuck], row-major */)
{
    extern __shared__ int hist[]; // nbuck ints
    for (int i = threadIdx.x; i < nbuck; i += ABLK) hist[i] = 0;
    __syncthreads();
    long e0 = (long)blockIdx.x * EPB;
    long e1 = e0 + EPB; if (e1 > E) e1 = E;
    for (long e = e0 + threadIdx.x; e < e1; e += ABLK) {
        int r = receivers[e];
        atomicAdd(&hist[r >> 7], 1);
    }
    __syncthreads();
    int* row = cnt + (long)blockIdx.x * nbuck;
    for (int i = threadIdx.x; i < nbuck; i += ABLK) row[i] = hist[i];
}

// ---------------- pass S1: exclusive scan down each bucket column ----------------
__global__ __launch_bounds__(SBLK) void passS1_colscan(
    int* __restrict__ cnt, int nblk, int nbuck, int* __restrict__ totals)
{
    int b = blockIdx.x;
    int t = threadIdx.x;
    __shared__ int csum[SBLK];
    int per = (nblk + SBLK - 1) / SBLK;
    int i0 = t * per;
    int i1 = i0 + per; if (i1 > nblk) i1 = nblk;
    int s = 0;
    for (int i = i0; i < i1; ++i) s += cnt[(long)i * nbuck + b];
    csum[t] = s;
    __syncthreads();
    for (int off = 1; off < SBLK; off <<= 1) {
        int add = (t >= off) ? csum[t - off] : 0;
        __syncthreads();
        csum[t] += add;
        __syncthreads();
    }
    int run = csum[t] - s;
    for (int i = i0; i < i1; ++i) {
        long a = (long)i * nbuck + b;
        int tmp = cnt[a];
        cnt[a] = run;
        run += tmp;
    }
    if (t == SBLK - 1) totals[b] = csum[SBLK - 1];
}

// ---------------- pass S2: exclusive scan over bucket totals ----------------
__global__ __launch_bounds__(1024) void passS2_basescan(
    const int* __restrict__ totals, int* __restrict__ base, int nbuck)
{
    __shared__ int sh[1024];
    int t = threadIdx.x;
    int v = (t < nbuck) ? totals[t] : 0;
    sh[t] = v;
    __syncthreads();
    for (int off = 1; off < 1024; off <<= 1) {
        int add = (t >= off) ? sh[t - off] : 0;
        __syncthreads();
        sh[t] += add;
        __syncthreads();
    }
    if (t < nbuck) base[t] = sh[t] - v;
}

// ---------------- pass B: scatter edge ids into bucket-sorted order ----------------
__global__ __launch_bounds__(ABLK) void passB_scatter(
    const int* __restrict__ receivers, long E, int nbuck,
    const int* __restrict__ cnt, const int* __restrict__ base,
    unsigned int* __restrict__ sorted)
{
    extern __shared__ int cur[];
    const int* row = cnt + (long)blockIdx.x * nbuck;
    for (int i = threadIdx.x; i < nbuck; i += ABLK) cur[i] = row[i] + base[i];
    __syncthreads();
    long e0 = (long)blockIdx.x * EPB;
    long e1 = e0 + EPB; if (e1 > E) e1 = E;
    for (long e = e0 + threadIdx.x; e < e1; e += ABLK) {
        int r = receivers[e];
        int b = r >> 7;
        int pos = atomicAdd(&cur[b], 1);
        sorted[pos] = ((unsigned)e << 7) | (unsigned)(r & 127);
    }
}

// -------- helpers --------
__device__ __forceinline__ void build_weights(
    int t,
    const float* __restrict__ bn_scale, const float* __restrict__ bn_bias,
    const float* __restrict__ bn_mean,  const float* __restrict__ bn_var,
    const float* __restrict__ W1, const float* __restrict__ b1,
    const float* __restrict__ W2, const float* __restrict__ b2,
    float* sW1, float* sW2, float* sB1, float* sB2)
{
    if (t < D * D) {
        int d = t / D;
        float a = bn_scale[d] * rsqrtf(bn_var[d] + 1e-5f);
        sW1[t] = a * W1[t];
        sW2[t] = W2[t];
    }
    if (t < D) {
        float acc = b1[t];
        #pragma unroll
        for (int d = 0; d < D; ++d) {
            float a = bn_scale[d] * rsqrtf(bn_var[d] + 1e-5f);
            float c = bn_bias[d] - bn_mean[d] * a;
            acc += c * W1[d * D + t];
        }
        sB1[t] = acc;
        sB2[t] = b2[t];
    }
}

__device__ __forceinline__ void mlp12(
    const float x[D],
    const float* sW1, const float* sW2, const float* sB1, const float* sB2,
    float y[D])
{
    float h[D];
    #pragma unroll
    for (int j = 0; j < D; ++j) h[j] = sB1[j];
    #pragma unroll
    for (int d = 0; d < D; ++d) {
        float xd = x[d];
        #pragma unroll
        for (int j = 0; j < D; ++j) h[j] = fmaf(xd, sW1[d * D + j], h[j]);
    }
    #pragma unroll
    for (int j = 0; j < D; ++j) h[j] = fmaxf(h[j], 0.f);
    #pragma unroll
    for (int j = 0; j < D; ++j) y[j] = sB2[j];
    #pragma unroll
    for (int d = 0; d < D; ++d) {
        float hd = h[d];
        #pragma unroll
        for (int j = 0; j < D; ++j) y[j] = fmaf(hd, sW2[d * D + j], y[j]);
    }
}

// ---------------- pass C: in-LDS node sort + register accumulation ----------------
// Removes the 76.8M f32 LDS atomics (measured ~150 G lane-atomics/s floor across
// rounds 3/5/6). Each thread owns a contiguous range of the node-sorted list,
// accumulates in registers, flushes to LDS only at node boundaries (~1.5/thread).
__global__ __launch_bounds__(CBLK) void passC_nodesort(
    const float* __restrict__ edges,
    const unsigned int* __restrict__ sortedG,
    const int* __restrict__ base, const int* __restrict__ totals,
    const float* __restrict__ bn_scale, const float* __restrict__ bn_bias,
    const float* __restrict__ bn_mean,  const float* __restrict__ bn_var,
    const float* __restrict__ W1, const float* __restrict__ b1,
    const float* __restrict__ W2, const float* __restrict__ b2,
    float* __restrict__ out, long total /* N*D */)
{
    __shared__ float sW1[D * D], sW2[D * D], sB1[D], sB2[D];
    __shared__ int hist[NPB];
    __shared__ int off[NPB + 1];
    __shared__ int cur[NPB];
    __shared__ unsigned sorted2[CAP];
    __shared__ float facc[NPB * ASTR];

    const int t = threadIdx.x;
    build_weights(t, bn_scale, bn_bias, bn_mean, bn_var, W1, b1, W2, b2,
                  sW1, sW2, sB1, sB2);
    for (int i = t; i < NPB * ASTR; i += CBLK) facc[i] = 0.f;
    if (t < NPB) hist[t] = 0;
    __syncthreads();

    const int b = blockIdx.x;
    const int s0 = base[b];
    const int n  = totals[b];

    if (n <= CAP) {
        // phase 1: node histogram (int LDS atomics: 1 per message)
        for (int k = t; k < n; k += CBLK)
            atomicAdd(&hist[sortedG[s0 + k] & (NPB - 1)], 1);
        __syncthreads();

        // phase 2: exclusive scan over 128 counters (Hillis-Steele)
        int myh = (t < NPB) ? hist[t] : 0;
        if (t < NPB) off[t] = myh;
        __syncthreads();
        for (int d2 = 1; d2 < NPB; d2 <<= 1) {
            int add = 0;
            if (t < NPB && t >= d2) add = off[t - d2];
            __syncthreads();
            if (t < NPB) off[t] += add;
            __syncthreads();
        }
        if (t < NPB) {
            int excl = off[t] - myh;
            cur[t] = excl;
        }
        __syncthreads();
        if (t < NPB) off[t] = cur[t];
        if (t == 0) off[NPB] = n;
        __syncthreads();

        // phase 3: scatter edge indices into node-sorted LDS order
        for (int k = t; k < n; k += CBLK) {
            unsigned e = sortedG[s0 + k];
            int pos = atomicAdd(&cur[e & (NPB - 1)], 1);
            sorted2[pos] = e >> 7;
        }
        __syncthreads();

        // phase 4: contiguous-range gather + MLP + register accumulation
        const int per = (n + CBLK - 1) / CBLK;
        int k0 = t * per;
        int k1 = k0 + per; if (k1 > n) k1 = n;
        if (k0 < k1) {
            int cu = 0;
            while (off[cu + 1] <= k0) ++cu;
            int nodeEnd = off[cu + 1];

            float ac[D];
            #pragma unroll
            for (int j = 0; j < D; ++j) ac[j] = 0.f;

            unsigned idx = sorted2[k0];
            const float4* p = reinterpret_cast<const float4*>(edges + (long)idx * D);
            float4 c0 = p[0], c1 = p[1], c2 = p[2];

            for (int k = k0; k < k1; ++k) {
                float4 n0 = c0, n1 = c1, n2 = c2;
                if (k + 1 < k1) {
                    unsigned ix = sorted2[k + 1];
                    const float4* q = reinterpret_cast<const float4*>(edges + (long)ix * D);
                    n0 = q[0]; n1 = q[1]; n2 = q[2];
                }
                if (k >= nodeEnd) {
                    #pragma unroll
                    for (int j = 0; j < D; ++j) {
                        atomicAdd(&facc[cu * ASTR + j], ac[j]);
                        ac[j] = 0.f;
                    }
                    do { ++cu; } while (off[cu + 1] <= k);
                    nodeEnd = off[cu + 1];
                }
                float x[D] = {c0.x, c0.y, c0.z, c0.w, c1.x, c1.y, c1.z, c1.w,
                              c2.x, c2.y, c2.z, c2.w};
                float y[D];
                mlp12(x, sW1, sW2, sB1, sB2, y);
                #pragma unroll
                for (int j = 0; j < D; ++j) ac[j] += y[j];
                c0 = n0; c1 = n1; c2 = n2;
            }
            #pragma unroll
            for (int j = 0; j < D; ++j) atomicAdd(&facc[cu * ASTR + j], ac[j]);
        }
    } else {
        // oversized bucket (shouldn't happen for uniform receivers): atomic path
        for (int k = t; k < n; k += CBLK) {
            unsigned e = sortedG[s0 + k];
            const float4* p = reinterpret_cast<const float4*>(edges + (long)(e >> 7) * D);
            float4 c0 = p[0], c1 = p[1], c2 = p[2];
            float x[D] = {c0.x, c0.y, c0.z, c0.w, c1.x, c1.y, c1.z, c1.w,
                          c2.x, c2.y, c2.z, c2.w};
            float y[D];
            mlp12(x, sW1, sW2, sB1, sB2, y);
            int rloc = (int)(e & (NPB - 1));
            #pragma unroll
            for (int j = 0; j < D; ++j) atomicAdd(&facc[rloc * ASTR + j], y[j]);
        }
    }
    __syncthreads();

    long obase = (long)b * (NPB * D);
    long cnt_w = total - obase; if (cnt_w > NPB * D) cnt_w = NPB * D;
    for (long i = t; i < cnt_w; i += CBLK)
        out[obase + i] = facc[((int)i / D) * ASTR + ((int)i % D)];
}

// ---------------- fallback: direct atomic scatter ----------------
#define EPT 4
__global__ __launch_bounds__(ABLK) void edge_mlp_scatter(
    const float* __restrict__ edges,
    const float* __restrict__ bn_scale, const float* __restrict__ bn_bias,
    const float* __restrict__ bn_mean,  const float* __restrict__ bn_var,
    const float* __restrict__ W1, const float* __restrict__ b1,
    const float* __restrict__ W2, const float* __restrict__ b2,
    const int* __restrict__ receivers, float* __restrict__ out, long E)
{
    __shared__ float sW1[D * D], sW2[D * D], sB1[D], sB2[D];
    const int t = threadIdx.x;
    build_weights(t, bn_scale, bn_bias, bn_mean, bn_var, W1, b1, W2, b2,
                  sW1, sW2, sB1, sB2);
    __syncthreads();
    const long basee = (long)blockIdx.x * (ABLK * EPT) + t;
    #pragma unroll
    for (int kk = 0; kk < EPT; ++kk) {
        long e = basee + (long)kk * ABLK;
        if (e >= E) continue;
        int r = receivers[e];
        const float4* p = reinterpret_cast<const float4*>(edges + e * D);
        float4 v0 = p[0], v1 = p[1], v2 = p[2];
        float x[D] = {v0.x, v0.y, v0.z, v0.w, v1.x, v1.y, v1.z, v1.w,
                      v2.x, v2.y, v2.z, v2.w};
        float y[D];
        mlp12(x, sW1, sW2, sB1, sB2, y);
        #pragma unroll
        for (int j = 0; j < D; ++j) atomicAdd(&out[(long)r * D + j], y[j]);
    }
}

extern "C" void kernel_launch(void* const* d_in, const int* in_sizes, int n_in,
                              void* d_out, int out_size, void* d_ws, size_t ws_size,
                              hipStream_t stream) {
    const float* edges     = (const float*)d_in[0];
    const float* bn_scale  = (const float*)d_in[1];
    const float* bn_bias   = (const float*)d_in[2];
    const float* bn_mean   = (const float*)d_in[3];
    const float* bn_var    = (const float*)d_in[4];
    const float* W1        = (const float*)d_in[5];
    const float* b1        = (const float*)d_in[6];
    const float* W2        = (const float*)d_in[7];
    const float* b2        = (const float*)d_in[8];
    const int*   receivers = (const int*)d_in[9];
    float*       out       = (float*)d_out;

    const long E = (long)in_sizes[0] / D;
    const int  N = out_size / D;

    const int  nbuck = (N + NPB - 1) >> 7;
    const long nblk  = (E + EPB - 1) / EPB;
    const size_t cntBytes = (size_t)nblk * (size_t)nbuck * 4u;
    const size_t need = cntBytes + 2u * (size_t)nbuck * 4u + (size_t)E * 4u + 512u;
    const long total = (long)N * D;

    const bool shapeOK = (nbuck <= 1024) && (E < (1L << 25));

    if (shapeOK && ws_size >= need) {
        char* w = (char*)d_ws;
        int* cnt    = (int*)w;  w += cntBytes;
        int* totals = (int*)w;  w += (size_t)nbuck * 4u;
        int* basep  = (int*)w;  w += (size_t)nbuck * 4u;
        unsigned int* sortedG = (unsigned int*)w;

        const size_t lds = (size_t)nbuck * 4u;
        passA_hist    <<<dim3((unsigned)nblk), dim3(ABLK), lds, stream>>>(receivers, E, nbuck, cnt);
        passS1_colscan<<<dim3((unsigned)nbuck), dim3(SBLK), 0, stream>>>(cnt, (int)nblk, nbuck, totals);
        passS2_basescan<<<dim3(1), dim3(1024), 0, stream>>>(totals, basep, nbuck);
        passB_scatter <<<dim3((unsigned)nblk), dim3(ABLK), lds, stream>>>(receivers, E, nbuck, cnt, basep, sortedG);
        passC_nodesort<<<dim3((unsigned)nbuck), dim3(CBLK), 0, stream>>>(
            edges, sortedG, basep, totals,
            bn_scale, bn_bias, bn_mean, bn_var, W1, b1, W2, b2, out, total);
        return;
    }

    (void)hipMemsetAsync(d_out, 0, (size_t)out_size * sizeof(float), stream);
    const long blocks = (E + (long)(ABLK * EPT) - 1) / (long)(ABLK * EPT);
    edge_mlp_scatter<<<dim3((unsigned)blocks), dim3(ABLK), 0, stream>>>(
        edges, bn_scale, bn_bias, bn_mean, bn_var, W1, b1, W2, b2,
        receivers, out, E);
}